// Round 6
// baseline (489.323 us; speedup 1.0000x reference)
//
#include <hip/hip_runtime.h>

// LightGCN on MI355X (gfx950). Round 14.
// R13 post-mortem: spmm locality is AT its floor (layer-3 FETCH 239MB vs 230
// ideal) but VALUBusy=54%: the oct=4-rows design burns 32 FMAs/edge with only 8
// useful (4x cndmask waste). Fix: row-per-oct spmm (R8's proven inner: 8 rows/
// wave, 8 useful FMAs/edge, ~1.6 wave-inst/edge vs 5.75) fed by (row, col)-
// sorted CSR — within-row col order preserves the band sweep (oct progress ~
// band phase). Accepted costs: max-of-8-degree divergence (~35%, known from R8)
// and 2x band-phase spread (single-row degree CV 18% vs 9%).
// Also: partA1 fused into partA2 (chunk-local sort needs NO global offsets;
// only partBF does) — deletes a 19.2MB pass.
// partBF key: (rl, col>>12) = 9472 bins, single in-place LDS count array
// (37.9KB keeps 3 blocks/CU); emits rowptr[150001] + 4B edges {val12|col18}.

#define NUSERS 100000
#define NITEMS 50000
#define NTOT   150000
#define DIM    64
#define NNZ_E  4800000

#define RPB     256    // rows per bucket
#define RSH     8
#define NBUCK   586    // ceil(150000/256)
#define CHUNK_E 8192
#define NPART   ((NNZ_E + CHUNK_E - 1) / CHUNK_E) // 586
#define NCB     37     // column bands of 4096 cols (150000>>12 = 36)
#define CSH     12
#define NBIN    (RPB * NCB)    // 9472: (rl, cb)

__device__ __forceinline__ unsigned short benc(float f) {
    union { float f; unsigned u; } t; t.f = f;
    unsigned r = t.u + 0x7FFFu + ((t.u >> 16) & 1u);   // RNE
    return (unsigned short)(r >> 16);
}
__device__ __forceinline__ float blo(unsigned g) { return __uint_as_float(g << 16); }
__device__ __forceinline__ float bhi(unsigned g) { return __uint_as_float(g & 0xFFFF0000u); }

// ---- Fused Pass A: per-chunk hist + local scan + LDS bucket-sort + sequential
// writeback (amp 1.0). Writes cntmat[p][b] (for colscan1), segoff[p][b], tmp.
// tmp word: x = col | rl<<18 (rl 8 bits), y = fp32 val.
__global__ void __launch_bounds__(512)
partA2_kernel(const int* __restrict__ rows, const int* __restrict__ cols,
              const float* __restrict__ vals, int* __restrict__ cntmat,
              int* __restrict__ segoff, int2* __restrict__ tmp) {
    __shared__ int2 buf[CHUNK_E];          // 64 KB
    __shared__ int cnt[NBUCK];
    __shared__ int st[512];
    int p = blockIdx.x;
    int c0 = p * CHUNK_E;
    int c1 = c0 + CHUNK_E; if (c1 > NNZ_E) c1 = NNZ_E;
    int nb = c1 - c0;
    int tid = threadIdx.x;
    for (int k = tid; k < NBUCK; k += 512) cnt[k] = 0;
    __syncthreads();
    int rloc[16];
#pragma unroll
    for (int u = 0; u < 16; ++u) {
        int e = c0 + tid + u * 512;
        rloc[u] = (e < c1) ? rows[e] : -1;
        if (rloc[u] >= 0) atomicAdd(&cnt[rloc[u] >> RSH], 1);
    }
    __syncthreads();
    // exclusive scan of 586 bins, 2/thread
    int t0 = tid * 2;
    int cA = (t0     < NBUCK) ? cnt[t0]     : 0;
    int cB = (t0 + 1 < NBUCK) ? cnt[t0 + 1] : 0;
    int s = cA + cB;
    st[tid] = s;
    __syncthreads();
    for (int ofs = 1; ofs < 512; ofs <<= 1) {
        int a = (tid >= ofs) ? st[tid - ofs] : 0;
        __syncthreads();
        st[tid] += a;
        __syncthreads();
    }
    int P = st[tid] - s;
    if (t0 < NBUCK) {
        cnt[t0] = P;
        segoff[(size_t)p * NBUCK + t0] = P;
        cntmat[(size_t)p * NBUCK + t0] = cA;
    }
    if (t0 + 1 < NBUCK) {
        cnt[t0 + 1] = P + cA;
        segoff[(size_t)p * NBUCK + t0 + 1] = P + cA;
        cntmat[(size_t)p * NBUCK + t0 + 1] = cB;
    }
    __syncthreads();
#pragma unroll
    for (int u = 0; u < 16; ++u) {
        int e = c0 + tid + u * 512;
        if (rloc[u] >= 0) {
            int r = rloc[u];
            int b = r >> RSH, rl = r & (RPB - 1);
            int q = atomicAdd(&cnt[b], 1);
            buf[q] = make_int2(cols[e] | (rl << 18), __float_as_int(vals[e]));
        }
    }
    __syncthreads();
    for (int k = tid; k < nb; k += 512)
        tmp[c0 + k] = buf[k];              // fully sequential, coalesced
}

// ---- Per-bucket scan over chunks: runoffT[b][p] excl, [b][NPART] = total ----
__global__ void __launch_bounds__(1024)
colscan1_kernel(const int* __restrict__ cntmat, int* __restrict__ runoffT,
                int* __restrict__ colTotal) {
    __shared__ int t[1024];
    int b = blockIdx.x;
    int tid = threadIdx.x;
    int v = (tid < NPART) ? cntmat[(size_t)tid * NBUCK + b] : 0;
    t[tid] = v;
    __syncthreads();
    for (int ofs = 1; ofs < 1024; ofs <<= 1) {
        int a = (tid >= ofs) ? t[tid - ofs] : 0;
        __syncthreads();
        t[tid] += a;
        __syncthreads();
    }
    if (tid < NPART) runoffT[(size_t)b * (NPART + 1) + tid] = t[tid] - v;
    if (tid == NPART - 1) {
        runoffT[(size_t)b * (NPART + 1) + NPART] = t[tid];
        colTotal[b] = t[tid];
    }
}

// ---- Exclusive scan of colTotal (NBUCK=586) -> bptr[NBUCK+1] ----
__global__ void __launch_bounds__(1024)
colscan2_kernel(const int* __restrict__ colTotal, int* __restrict__ bptr) {
    __shared__ int t[1024];
    int tid = threadIdx.x;
    int v = (tid < NBUCK) ? colTotal[tid] : 0;
    t[tid] = v;
    __syncthreads();
    for (int ofs = 1; ofs < 1024; ofs <<= 1) {
        int a = (tid >= ofs) ? t[tid - ofs] : 0;
        __syncthreads();
        t[tid] += a;
        __syncthreads();
    }
    if (tid < NBUCK) bptr[tid] = t[tid] - v;
    if (tid == 1023) bptr[NBUCK] = t[1023];
}

// ---- Fused Phase B: gather bucket segments; counting sort by (rl, col>>12) ----
// Emits rowptr[150001] + fin 4B: col[0:17] | zero[18:19] | val12[20:31].
__global__ void __launch_bounds__(1024)
partBF_kernel(const int* __restrict__ bptr, const int* __restrict__ runoffT,
              const int* __restrict__ segoff, const int2* __restrict__ tmp,
              unsigned* __restrict__ fin, int* __restrict__ rowptr) {
    __shared__ int cnt[NBIN];              // 37.9 KB, in-place count->base->cursor
    __shared__ int st[1024];
    __shared__ int runoff[NPART + 1];
    __shared__ int soff[NPART];
    int b = blockIdx.x;
    int bb0 = bptr[b];
    int tid = threadIdx.x;
    for (int k = tid; k < NBIN; k += 1024) cnt[k] = 0;
    if (tid <= NPART) runoff[tid] = runoffT[(size_t)b * (NPART + 1) + tid];
    if (tid < NPART)  soff[tid]   = segoff[(size_t)tid * NBUCK + b];
    __syncthreads();
    int nb = runoff[NPART];
    // pass 1: histogram (rl, cb)
    for (int j = tid; j < nb; j += 1024) {
        int lo = 0, hi = NPART;
        while (hi - lo > 1) { int mid = (lo + hi) >> 1; if (runoff[mid] <= j) lo = mid; else hi = mid; }
        int src = lo * CHUNK_E + soff[lo] + (j - runoff[lo]);
        int x = tmp[src].x;
        int key = ((x >> 18) & 255) * NCB + ((x & 0x3FFFF) >> CSH);
        atomicAdd(&cnt[key], 1);
    }
    __syncthreads();
    // in-place exclusive scan of 9472 bins: 10 bins/thread + block scan
    int t0 = tid * 10;
    int c[10];
    int s = 0;
#pragma unroll
    for (int u = 0; u < 10; ++u) {
        int idx = t0 + u;
        c[u] = (idx < NBIN) ? cnt[idx] : 0;
        s += c[u];
    }
    st[tid] = s;
    __syncthreads();
    for (int ofs = 1; ofs < 1024; ofs <<= 1) {
        int a = (tid >= ofs) ? st[tid - ofs] : 0;
        __syncthreads();
        st[tid] += a;
        __syncthreads();
    }
    int P = st[tid] - s;
#pragma unroll
    for (int u = 0; u < 10; ++u) {
        int idx = t0 + u;
        if (idx < NBIN) { cnt[idx] = P; P += c[u]; }
    }
    __syncthreads();
    if (tid < RPB) {
        int r = b * RPB + tid;
        if (r < NTOT) rowptr[r] = bb0 + cnt[tid * NCB];
    }
    if (b == NBUCK - 1 && tid == 0) rowptr[NTOT] = bb0 + nb;
    __syncthreads();   // rowptr snapshot before cursors mutate
    // pass 2: gather again (L2-hot), scatter to fin
    for (int j = tid; j < nb; j += 1024) {
        int lo = 0, hi = NPART;
        while (hi - lo > 1) { int mid = (lo + hi) >> 1; if (runoff[mid] <= j) lo = mid; else hi = mid; }
        int src = lo * CHUNK_E + soff[lo] + (j - runoff[lo]);
        int2 t = tmp[src];
        int x = t.x;
        int key = ((x >> 18) & 255) * NCB + ((x & 0x3FFFF) >> CSH);
        int q = atomicAdd(&cnt[key], 1);
        unsigned qq = (unsigned)__float2int_rn(__int_as_float(t.y) * 4096.f);
        if (qq > 4095u) qq = 4095u;
        fin[bb0 + q] = ((unsigned)x & 0x3FFFFu) | (qq << 20);
    }
}

// ---- x0h bf16-packed: uint j of row r = comps (2j, 2j+1) ----
__global__ void convert_kernel(const float2* __restrict__ user, const float2* __restrict__ item,
                               unsigned* __restrict__ xh2) {
    int i = blockIdx.x * blockDim.x + threadIdx.x;   // = row*32 + j
    if (i >= NTOT * 32) return;
    float2 v = (i < NUSERS * 32) ? user[i] : item[i - NUSERS * 32];
    xh2[i] = (unsigned)benc(v.x) | ((unsigned)benc(v.y) << 16);
}

// ---- SpMM: 8 rows/wave (one per oct), register acc, col-sorted CSR, unroll 8 ----
__global__ void __launch_bounds__(256)
spmm_kernel(const int* __restrict__ rowptr, const unsigned* __restrict__ ed,
            const uint4* __restrict__ xin, uint4* __restrict__ yout,
            const float4* __restrict__ user, const float4* __restrict__ item,
            const uint4* __restrict__ y1, float4* __restrict__ out, int last) {
    int wid = blockIdx.x * (blockDim.x >> 6) + (threadIdx.x >> 6);
    int lane = threadIdx.x & 63;
    int oct = lane >> 3, s = lane & 7;
    int r = wid * 8 + oct;
    if (r >= NTOT) return;
    int start = rowptr[r];
    int end   = rowptr[r + 1];
    const float SCL = 1.f / 4096.f;
    float a0 = 0.f, a1 = 0.f, a2 = 0.f, a3 = 0.f, a4 = 0.f, a5 = 0.f, a6 = 0.f, a7 = 0.f;
    int i = start;
    for (; i + 8 <= end; i += 8) {
        unsigned e[8];
#pragma unroll
        for (int u = 0; u < 8; ++u) e[u] = ed[i + u];
        uint4 g[8];
#pragma unroll
        for (int u = 0; u < 8; ++u) g[u] = xin[(size_t)(e[u] & 0x3FFFFu) * 8 + s];
#pragma unroll
        for (int u = 0; u < 8; ++u) {
            float v = (float)(e[u] >> 20) * SCL;
            a0 += v * blo(g[u].x); a1 += v * bhi(g[u].x);
            a2 += v * blo(g[u].y); a3 += v * bhi(g[u].y);
            a4 += v * blo(g[u].z); a5 += v * bhi(g[u].z);
            a6 += v * blo(g[u].w); a7 += v * bhi(g[u].w);
        }
    }
    for (; i < end; ++i) {
        unsigned e = ed[i];
        uint4 g = xin[(size_t)(e & 0x3FFFFu) * 8 + s];
        float v = (float)(e >> 20) * SCL;
        a0 += v * blo(g.x); a1 += v * bhi(g.x);
        a2 += v * blo(g.y); a3 += v * bhi(g.y);
        a4 += v * blo(g.z); a5 += v * bhi(g.z);
        a6 += v * blo(g.w); a7 += v * bhi(g.w);
    }
    if (!last) {
        uint4 o;
        o.x = (unsigned)benc(a0) | ((unsigned)benc(a1) << 16);
        o.y = (unsigned)benc(a2) | ((unsigned)benc(a3) << 16);
        o.z = (unsigned)benc(a4) | ((unsigned)benc(a5) << 16);
        o.w = (unsigned)benc(a6) | ((unsigned)benc(a7) << 16);
        yout[(size_t)r * 8 + s] = o;
    } else {
        size_t f4 = (size_t)r * 16 + 2 * s;   // float4 index of comps [8s, 8s+8)
        float4 x0a = (r < NUSERS) ? user[f4]     : item[f4     - (size_t)NUSERS * 16];
        float4 x0b = (r < NUSERS) ? user[f4 + 1] : item[f4 + 1 - (size_t)NUSERS * 16];
        uint4 u1 = y1[(size_t)r * 8 + s];
        uint4 u2 = xin[(size_t)r * 8 + s];   // layer-3 input IS y2
        float4 oa, ob;
        oa.x = 0.25f * (x0a.x + blo(u1.x) + blo(u2.x) + a0);
        oa.y = 0.25f * (x0a.y + bhi(u1.x) + bhi(u2.x) + a1);
        oa.z = 0.25f * (x0a.z + blo(u1.y) + blo(u2.y) + a2);
        oa.w = 0.25f * (x0a.w + bhi(u1.y) + bhi(u2.y) + a3);
        ob.x = 0.25f * (x0b.x + blo(u1.z) + blo(u2.z) + a4);
        ob.y = 0.25f * (x0b.y + bhi(u1.z) + bhi(u2.z) + a5);
        ob.z = 0.25f * (x0b.z + blo(u1.w) + blo(u2.w) + a6);
        ob.w = 0.25f * (x0b.w + bhi(u1.w) + bhi(u2.w) + a7);
        out[f4]     = oa;
        out[f4 + 1] = ob;
    }
}

extern "C" void kernel_launch(void* const* d_in, const int* in_sizes, int n_in,
                              void* d_out, int out_size, void* d_ws, size_t ws_size,
                              hipStream_t stream) {
    const float* user = (const float*)d_in[0];
    const float* item = (const float*)d_in[1];
    const float* vals = (const float*)d_in[2];
    const int*   rows = (const int*)d_in[3];
    const int*   cols = (const int*)d_in[4];
    float* out = (float*)d_out;

    // ws layout (~101 MB): tmp 38.4M | fin 19.2M | bufA 19.2M | bufB 19.2M |
    // cntmat 1.37M | runoffT 1.38M | segoff 1.37M | rowptr 600K | colTotal | bptr
    char* w = (char*)d_ws;
    int2*     tmp      = (int2*)w;     w += (size_t)NNZ_E * 8;
    unsigned* fin      = (unsigned*)w; w += (size_t)NNZ_E * 4;
    unsigned* bufA     = (unsigned*)w; w += (size_t)NTOT * DIM * 2;   // x0h, later y2h
    unsigned* bufB     = (unsigned*)w; w += (size_t)NTOT * DIM * 2;   // y1h
    int*      cntmat   = (int*)w;      w += (size_t)NPART * NBUCK * 4;
    int*      runoffT  = (int*)w;      w += (size_t)NBUCK * (NPART + 1) * 4;
    int*      segoff   = (int*)w;      w += (size_t)NPART * NBUCK * 4;
    int*      rowptr   = (int*)w;      w += (size_t)(NTOT + 1) * 4;
    int*      colTotal = (int*)w;      w += (size_t)NBUCK * 4;
    int*      bptr     = (int*)w;

    const int blk = 256;
    const int gConv = (NTOT * 32 + blk - 1) / blk;       // 18750
    const int gSpmm = (NTOT / 8 + 3) / 4;                // 4688 (4 waves/block, 8 rows/wave)

    partA2_kernel<<<NPART, 512, 0, stream>>>(rows, cols, vals, cntmat, segoff, tmp);
    colscan1_kernel<<<NBUCK, 1024, 0, stream>>>(cntmat, runoffT, colTotal);
    colscan2_kernel<<<1, 1024, 0, stream>>>(colTotal, bptr);
    partBF_kernel<<<NBUCK, 1024, 0, stream>>>(bptr, runoffT, segoff, tmp, fin, rowptr);

    convert_kernel<<<gConv, blk, 0, stream>>>((const float2*)user, (const float2*)item, bufA);

    spmm_kernel<<<gSpmm, blk, 0, stream>>>(rowptr, fin, (const uint4*)bufA, (uint4*)bufB,
                                           (const float4*)user, (const float4*)item,
                                           (const uint4*)bufB, (float4*)out, 0); // y1=bufB
    spmm_kernel<<<gSpmm, blk, 0, stream>>>(rowptr, fin, (const uint4*)bufB, (uint4*)bufA,
                                           (const float4*)user, (const float4*)item,
                                           (const uint4*)bufB, (float4*)out, 0); // y2=bufA
    spmm_kernel<<<gSpmm, blk, 0, stream>>>(rowptr, fin, (const uint4*)bufA, (uint4*)bufA,
                                           (const float4*)user, (const float4*)item,
                                           (const uint4*)bufB, (float4*)out, 1); // fused mean
}